// Round 1
// baseline (188.674 us; speedup 1.0000x reference)
//
#include <hip/hip_runtime.h>

// CrossWarpingModule: 4-phase pixel-unshuffle -> axial attention (8 heads, c=1)
// -> flow -> bilinear border grid_sample -> pixel-shuffle back.
// B=2, C=64, H=W=256; sub-images: 8 x [64][128][128].
//
// R7 = R6 with the attn staging overflow fixed (256 float4s, single pass).
// attn: LOG2E pre-folded into Wk (qkv), float4 staging, packed float2
// accumulators, slim 2-partial epilogue. warp: x-tap pair fetched as one
// float4 per row (VMEM halved), cndmask tap select with border handling.
//
// R8: identical resubmission of R7 — previous round's bench failed on
// infrastructure (container), no counters were produced. Re-establishing
// the 186.2us baseline + rocprof evidence before the next edit.

constexpr int PLANE = 16384;                 // 128*128
constexpr float LOG2E = 1.4426950408889634f;

typedef float v2f __attribute__((ext_vector_type(2)));

// ---------------------------------------------------------------------------
// Kernel 1: q/k/v projection. Block = (b, Y, X-half): 128 contiguous X
// positions x 4 channel-groups (16 ch each). Tree-reduce in LDS.
// K is written pre-scaled by log2(e) (consumed only via exp2 in attn).
// grid 1024 x 512.
// ---------------------------------------------------------------------------
__global__ __launch_bounds__(512) void qkv_kernel(
    const float* __restrict__ cur, const float* __restrict__ ref,
    const float* __restrict__ Wq, const float* __restrict__ Wk,
    const float* __restrict__ Wv,
    float* __restrict__ Q, float* __restrict__ K, float* __restrict__ V)
{
    __shared__ float WT[64 * 24];       // WT[c][j]: j<8 Wq, <16 Wk*log2e, <24 Wv
    __shared__ float red0[128 * 25];    // stride 25: conflict-free
    __shared__ float red1[128 * 25];
    const int tid = threadIdx.x;
    for (int i = tid; i < 64 * 24; i += 512) {
        int c = i / 24, j = i % 24;
        float val = (j < 8) ? Wq[j * 64 + c]
                  : (j < 16) ? LOG2E * Wk[(j - 8) * 64 + c]
                  : Wv[(j - 16) * 64 + c];
        WT[c * 24 + j] = val;
    }
    __syncthreads();

    const int bi = blockIdx.x;               // 0..1023
    const int b  = bi >> 9;                  // batch
    const int Y  = (bi >> 1) & 255;          // full-res row
    const int Xh = bi & 1;                   // X half
    const int cg = tid >> 7;                 // channel group 0..3
    const int xi = tid & 127;
    const int X  = Xh * 128 + xi;            // full-res col (contiguous/lane)

    const size_t base_in = (size_t)b * 64 * 65536 + (size_t)Y * 256 + X;
    const float* curp = cur + base_in;
    const float* refp = ref + base_in;

    float q[8], k[8], v[8];
#pragma unroll
    for (int i = 0; i < 8; ++i) { q[i] = 0.f; k[i] = 0.f; v[i] = 0.f; }

    const int c0 = cg * 16;
#pragma unroll 8
    for (int c = 0; c < 16; ++c) {
        float cu = curp[(size_t)(c0 + c) * 65536];
        float rf = refp[(size_t)(c0 + c) * 65536];
        const float* wr = &WT[(c0 + c) * 24];
#pragma unroll
        for (int i = 0; i < 8; ++i) {
            q[i] = fmaf(wr[i],      cu, q[i]);
            k[i] = fmaf(wr[8 + i],  rf, k[i]);
            v[i] = fmaf(wr[16 + i], rf, v[i]);
        }
    }

    // tree reduce: (1 -> red0), (3 -> red1); (2 += red1); (0 += red0+red1)
    float* row0 = &red0[xi * 25];
    float* row1 = &red1[xi * 25];
    if (cg == 1) {
#pragma unroll
        for (int i = 0; i < 8; ++i) {
            row0[i] = q[i]; row0[8 + i] = k[i]; row0[16 + i] = v[i];
        }
    } else if (cg == 3) {
#pragma unroll
        for (int i = 0; i < 8; ++i) {
            row1[i] = q[i]; row1[8 + i] = k[i]; row1[16 + i] = v[i];
        }
    }
    __syncthreads();
    if (cg == 2) {
#pragma unroll
        for (int i = 0; i < 8; ++i) {
            row1[i]      += q[i];
            row1[8 + i]  += k[i];
            row1[16 + i] += v[i];
        }
    } else if (cg == 0) {
#pragma unroll
        for (int i = 0; i < 8; ++i) {
            q[i] += row0[i]; k[i] += row0[8 + i]; v[i] += row0[16 + i];
        }
    }
    __syncthreads();
    if (cg == 0) {
        const int dy = Y & 1, dx = X & 1;
        // (dy,dx)->phase: (0,0)=0 (1,1)=1 (0,1)=2 (1,0)=3
        const int p  = dy ? (dx ? 1 : 3) : (dx ? 2 : 0);
        const int sb = p * 2 + b;
        const int h = Y >> 1, w = X >> 1;
#pragma unroll
        for (int i = 0; i < 8; ++i) {
            const size_t o = ((size_t)(sb * 8 + i) << 14) + (h << 7) + w;
            Q[o] = q[i] + row1[i];
            K[o] = k[i] + row1[8 + i];
            V[o] = v[i] + row1[16 + i];
        }
    }
}

// ---------------------------------------------------------------------------
// Kernel 2: per-plane 128x128 transpose of Q,K,V -> QT,KT,VT. 32x32 LDS
// tiles, coalesced float4 on both sides. grid 1024 x 256.
// ---------------------------------------------------------------------------
__global__ __launch_bounds__(256) void transpose_kernel(
    const float* __restrict__ Q, const float* __restrict__ K,
    const float* __restrict__ V,
    float* __restrict__ QT, float* __restrict__ KT, float* __restrict__ VT)
{
    __shared__ float tile[32 * 33];
    const int bi = blockIdx.x;         // 0..1023
    const int plane = bi >> 4;         // (sb*8+head)
    const int ti = (bi >> 2) & 3, tj = bi & 3;
    const int t = threadIdx.x;
    const int r = t >> 3, c4 = (t & 7) * 4;     // 32 rows x 8 float4 cols
    const size_t pb = (size_t)plane << 14;
    const size_t ibase = pb + (size_t)(ti * 32) * 128 + tj * 32;
    const size_t obase = pb + (size_t)(tj * 32) * 128 + ti * 32;

    const float* srcs[3] = { Q, K, V };
    float* dsts[3] = { QT, KT, VT };
#pragma unroll
    for (int a = 0; a < 3; ++a) {
        const float* src = srcs[a];
        float* dst = dsts[a];
        const float4 val = *(const float4*)&src[ibase + (size_t)r * 128 + c4];
        if (a) __syncthreads();
        tile[r * 33 + c4 + 0] = val.x;
        tile[r * 33 + c4 + 1] = val.y;
        tile[r * 33 + c4 + 2] = val.z;
        tile[r * 33 + c4 + 3] = val.w;
        __syncthreads();
        float4 o;
        o.x = tile[(c4 + 0) * 33 + r];
        o.y = tile[(c4 + 1) * 33 + r];
        o.z = tile[(c4 + 2) * 33 + r];
        o.w = tile[(c4 + 3) * 33 + r];
        *(float4*)&dst[obase + (size_t)r * 128 + c4] = o;
    }
}

// ---------------------------------------------------------------------------
// Kernel 3: both axial attention passes + 8->1 head projection, fused.
// Block = (pass, sb, line), 256 threads = (sub = tid>>7, t = tid&127);
// thread handles heads {sub*4..sub*4+3}; head wave-uniform -> LDS reads are
// broadcast ds_read_b128. K already pre-scaled by log2e. Packed float2
// accumulators. Epilogue: 2-partial weighted-sum add.
// Staging: kk/vv are 256 float4s each -> exactly one float4 per thread.
// grid 2048 x 256.
// ---------------------------------------------------------------------------
__global__ __launch_bounds__(256) void attn_fused(
    const float* __restrict__ Q, const float* __restrict__ K,
    const float* __restrict__ V,
    const float* __restrict__ QT, const float* __restrict__ KT,
    const float* __restrict__ VT,
    const float* __restrict__ Whor, const float* __restrict__ Wver,
    float* __restrict__ OH, float* __restrict__ OVT)
{
    __shared__ __align__(16) float kk[8 * 128];   // pre-scaled by log2(e)
    __shared__ __align__(16) float vv[8 * 128];
    __shared__ float part[128];                   // sub=1 partial sums

    const int pass = blockIdx.x >> 10;
    const float* __restrict__ Qa = pass ? QT : Q;
    const float* __restrict__ Ka = pass ? KT : K;
    const float* __restrict__ Va = pass ? VT : V;
    const float* __restrict__ wsel = pass ? Wver : Whor;
    float* __restrict__ o = pass ? OVT : OH;

    const int tid  = threadIdx.x;
    const int sub  = tid >> 7;          // head group 0/1 (wave-uniform)
    const int t    = tid & 127;
    const int sbl  = blockIdx.x & 1023;
    const int sb   = sbl >> 7;
    const int line = sbl & 127;

    const size_t base = (((size_t)(sb * 8)) << 14) + ((size_t)line << 7);
    // stage all 8 heads' k,v rows: 256 float4s per array, one per thread.
    {
        const int f  = tid;                       // float4 id, 0..255
        const int hh = f >> 5;                    // head 0..7
        const int tt = (f & 31) << 2;             // element 0..124
        const size_t g = base + ((size_t)hh << 14) + tt;
        ((float4*)kk)[f] = *(const float4*)&Ka[g];
        ((float4*)vv)[f] = *(const float4*)&Va[g];
    }
    __syncthreads();

    float acc = 0.f;
#pragma unroll
    for (int i = 0; i < 4; ++i) {
        const int head = sub * 4 + i;             // wave-uniform
        const float s = Qa[base + ((size_t)head << 14) + t];
        const float4* k4 = (const float4*)&kk[head << 7];
        const float4* v4 = (const float4*)&vv[head << 7];
        v2f d01 = {0.f, 0.f}, d23 = {0.f, 0.f};
        v2f n01 = {0.f, 0.f}, n23 = {0.f, 0.f};
#pragma unroll 8
        for (int l = 0; l < 32; ++l) {
            const float4 kq = k4[l];
            const float4 vq = v4[l];
            v2f a01 = {s * kq.x, s * kq.y};
            v2f a23 = {s * kq.z, s * kq.w};
            v2f e01 = {__builtin_amdgcn_exp2f(a01.x), __builtin_amdgcn_exp2f(a01.y)};
            v2f e23 = {__builtin_amdgcn_exp2f(a23.x), __builtin_amdgcn_exp2f(a23.y)};
            d01 += e01;
            d23 += e23;
            n01 += e01 * (v2f){vq.x, vq.y};
            n23 += e23 * (v2f){vq.z, vq.w};
        }
        const v2f dv = d01 + d23, nv = n01 + n23;
        const float den = dv.x + dv.y;
        const float num = nv.x + nv.y;
        acc = fmaf(wsel[head], num * __builtin_amdgcn_rcpf(den), acc);
    }

    if (sub) part[t] = acc;
    __syncthreads();
    if (!sub) {
        o[((size_t)sb << 14) + ((size_t)line << 7) + t] = acc + part[t];
    }
}

// ---------------------------------------------------------------------------
// Kernel 4: warp, output-major. Block = (b, cgroup, Y); lane = X. Stores are
// contiguous full-res rows. Both x-taps (cols 2*x0c+dx, 2*x1c+dx) fetched as
// ONE float4 per row at col base cb=min(2*x0c,252) -> 2 dwordx4 per channel
// instead of 4 scalar loads; taps picked with cndmask (hi/up1 select covers
// border clamp). grid 2048 x 256.
// ---------------------------------------------------------------------------
__global__ __launch_bounds__(256) void warp_kernel(
    const float* __restrict__ ref, const float* __restrict__ ovt,
    const float* __restrict__ oh, float* __restrict__ out)
{
    const int bi = blockIdx.x;          // 0..2047
    const int Y  = bi & 255;
    const int cg = (bi >> 8) & 3;
    const int b  = bi >> 10;
    const int X  = threadIdx.x;

    const int dy = Y & 1, dx = X & 1;
    const int p  = dy ? (dx ? 1 : 3) : (dx ? 2 : 0);
    const int sb = p * 2 + b;
    const int h = Y >> 1, w = X >> 1;

    // normalized-coord round trip cancels exactly:
    const float ix = (float)w + oh [((size_t)sb << 14) + (h << 7) + w];
    const float iy = (float)h + ovt[((size_t)sb << 14) + (w << 7) + h];

    const float x0f = floorf(ix), y0f = floorf(iy);
    const float wx = ix - x0f,    wy = iy - y0f;
    const int x0 = (int)x0f, y0 = (int)y0f;
    const int x0c = min(max(x0, 0), 127),     x1c = min(max(x0 + 1, 0), 127);
    const int y0c = min(max(y0, 0), 127),     y1c = min(max(y0 + 1, 0), 127);

    const float w00 = (1.f - wx) * (1.f - wy);
    const float w01 = wx * (1.f - wy);
    const float w10 = (1.f - wx) * wy;
    const float w11 = wx * wy;

    const int cb  = min(2 * x0c, 252);      // float4 col base (8B-aligned ok)
    const bool hi  = (x0c == 127);          // taps live in upper half of f4
    const bool up1 = hi | (x1c != x0c);     // second tap uses upper element
    const int r0 = (2 * y0c + dy) * 256, r1 = (2 * y1c + dy) * 256;
    const int dst = Y * 256 + X;

    const float* rp = ref + ((size_t)b * 64 + cg * 16) * 65536;
    float* op = out + ((size_t)b * 64 + cg * 16) * 65536;

#pragma unroll 4
    for (int c = 0; c < 16; ++c) {
        const size_t pl = (size_t)c * 65536;
        const float4 f0 = *(const float4*)&rp[pl + r0 + cb];
        const float4 f1 = *(const float4*)&rp[pl + r1 + cb];
        const float L0 = dx ? f0.y : f0.x, H0 = dx ? f0.w : f0.z;
        const float L1 = dx ? f1.y : f1.x, H1 = dx ? f1.w : f1.z;
        const float v00 = hi ? H0 : L0,  v01 = up1 ? H0 : L0;
        const float v10 = hi ? H1 : L1,  v11 = up1 ? H1 : L1;
        op[pl + dst] = fmaf(w00, v00, fmaf(w01, v01, fmaf(w10, v10, w11 * v11)));
    }
}

// ---------------------------------------------------------------------------
extern "C" void kernel_launch(void* const* d_in, const int* in_sizes, int n_in,
                              void* d_out, int out_size, void* d_ws, size_t ws_size,
                              hipStream_t stream)
{
    const float* cur  = (const float*)d_in[0];
    const float* ref  = (const float*)d_in[1];
    const float* Wq   = (const float*)d_in[2];
    const float* Wk   = (const float*)d_in[3];
    const float* Wv   = (const float*)d_in[4];
    const float* Wver = (const float*)d_in[5];
    const float* Whor = (const float*)d_in[6];
    float* out = (float*)d_out;

    float* ws = (float*)d_ws;
    const size_t NQ = 8 * 8 * (size_t)PLANE;   // 1,048,576 floats
    float* Q   = ws;
    float* K   = Q  + NQ;                      // pre-scaled by log2(e)
    float* V   = K  + NQ;
    float* QT  = V  + NQ;
    float* KT  = QT + NQ;
    float* VT  = KT + NQ;
    float* OVT = VT + NQ;                      // [sb][w][h]
    float* OH  = OVT + 8 * (size_t)PLANE;      // [sb][h][w]

    qkv_kernel<<<1024, 512, 0, stream>>>(cur, ref, Wq, Wk, Wv, Q, K, V);
    transpose_kernel<<<1024, 256, 0, stream>>>(Q, K, V, QT, KT, VT);
    attn_fused<<<2048, 256, 0, stream>>>(Q, K, V, QT, KT, VT,
                                         Whor, Wver, OH, OVT);
    warp_kernel<<<2048, 256, 0, stream>>>(ref, OVT, OH, out);
}

// Round 2
// 188.660 us; speedup vs baseline: 1.0001x; 1.0001x over previous
//
#include <hip/hip_runtime.h>

// CrossWarpingModule: 4-phase pixel-unshuffle -> axial attention (8 heads, c=1)
// -> flow -> bilinear border grid_sample -> pixel-shuffle back.
// B=2, C=64, H=W=256; sub-images: 8 x [64][128][128].
//
// R9 = R7/R8 with attn_fused inner loop rewritten on packed FP32:
// v_pk_mul/add/fma_f32 via inline asm (clang scalarizes v2f and never forms
// VOP3P f32 on its own — measured VALUBusy matched the unpacked count).
// LDS consumed as v2f (ds_read_b64) so pk operands are native pairs.
// Issue demand per wave drops 7168 -> 5632 cycles; exp pipe (quarter-rate)
// becomes the floor.

constexpr int PLANE = 16384;                 // 128*128
constexpr float LOG2E = 1.4426950408889634f;

typedef float v2f __attribute__((ext_vector_type(2)));

// Packed fp32 helpers (full-rate on CDNA2+; 2 f32 ops / instr).
static __device__ __forceinline__ v2f pk_mul(v2f a, v2f b) {
    v2f d;
    asm("v_pk_mul_f32 %0, %1, %2" : "=v"(d) : "v"(a), "v"(b));
    return d;
}
static __device__ __forceinline__ v2f pk_add(v2f a, v2f b) {
    v2f d;
    asm("v_pk_add_f32 %0, %1, %2" : "=v"(d) : "v"(a), "v"(b));
    return d;
}
static __device__ __forceinline__ v2f pk_fma(v2f a, v2f b, v2f c) {
    v2f d;
    asm("v_pk_fma_f32 %0, %1, %2, %3" : "=v"(d) : "v"(a), "v"(b), "v"(c));
    return d;
}

// ---------------------------------------------------------------------------
// Kernel 1: q/k/v projection. Block = (b, Y, X-half): 128 contiguous X
// positions x 4 channel-groups (16 ch each). Tree-reduce in LDS.
// K is written pre-scaled by log2(e) (consumed only via exp2 in attn).
// grid 1024 x 512.
// ---------------------------------------------------------------------------
__global__ __launch_bounds__(512) void qkv_kernel(
    const float* __restrict__ cur, const float* __restrict__ ref,
    const float* __restrict__ Wq, const float* __restrict__ Wk,
    const float* __restrict__ Wv,
    float* __restrict__ Q, float* __restrict__ K, float* __restrict__ V)
{
    __shared__ float WT[64 * 24];       // WT[c][j]: j<8 Wq, <16 Wk*log2e, <24 Wv
    __shared__ float red0[128 * 25];    // stride 25: conflict-free
    __shared__ float red1[128 * 25];
    const int tid = threadIdx.x;
    for (int i = tid; i < 64 * 24; i += 512) {
        int c = i / 24, j = i % 24;
        float val = (j < 8) ? Wq[j * 64 + c]
                  : (j < 16) ? LOG2E * Wk[(j - 8) * 64 + c]
                  : Wv[(j - 16) * 64 + c];
        WT[c * 24 + j] = val;
    }
    __syncthreads();

    const int bi = blockIdx.x;               // 0..1023
    const int b  = bi >> 9;                  // batch
    const int Y  = (bi >> 1) & 255;          // full-res row
    const int Xh = bi & 1;                   // X half
    const int cg = tid >> 7;                 // channel group 0..3
    const int xi = tid & 127;
    const int X  = Xh * 128 + xi;            // full-res col (contiguous/lane)

    const size_t base_in = (size_t)b * 64 * 65536 + (size_t)Y * 256 + X;
    const float* curp = cur + base_in;
    const float* refp = ref + base_in;

    float q[8], k[8], v[8];
#pragma unroll
    for (int i = 0; i < 8; ++i) { q[i] = 0.f; k[i] = 0.f; v[i] = 0.f; }

    const int c0 = cg * 16;
#pragma unroll 8
    for (int c = 0; c < 16; ++c) {
        float cu = curp[(size_t)(c0 + c) * 65536];
        float rf = refp[(size_t)(c0 + c) * 65536];
        const float* wr = &WT[(c0 + c) * 24];
#pragma unroll
        for (int i = 0; i < 8; ++i) {
            q[i] = fmaf(wr[i],      cu, q[i]);
            k[i] = fmaf(wr[8 + i],  rf, k[i]);
            v[i] = fmaf(wr[16 + i], rf, v[i]);
        }
    }

    // tree reduce: (1 -> red0), (3 -> red1); (2 += red1); (0 += red0+red1)
    float* row0 = &red0[xi * 25];
    float* row1 = &red1[xi * 25];
    if (cg == 1) {
#pragma unroll
        for (int i = 0; i < 8; ++i) {
            row0[i] = q[i]; row0[8 + i] = k[i]; row0[16 + i] = v[i];
        }
    } else if (cg == 3) {
#pragma unroll
        for (int i = 0; i < 8; ++i) {
            row1[i] = q[i]; row1[8 + i] = k[i]; row1[16 + i] = v[i];
        }
    }
    __syncthreads();
    if (cg == 2) {
#pragma unroll
        for (int i = 0; i < 8; ++i) {
            row1[i]      += q[i];
            row1[8 + i]  += k[i];
            row1[16 + i] += v[i];
        }
    } else if (cg == 0) {
#pragma unroll
        for (int i = 0; i < 8; ++i) {
            q[i] += row0[i]; k[i] += row0[8 + i]; v[i] += row0[16 + i];
        }
    }
    __syncthreads();
    if (cg == 0) {
        const int dy = Y & 1, dx = X & 1;
        // (dy,dx)->phase: (0,0)=0 (1,1)=1 (0,1)=2 (1,0)=3
        const int p  = dy ? (dx ? 1 : 3) : (dx ? 2 : 0);
        const int sb = p * 2 + b;
        const int h = Y >> 1, w = X >> 1;
#pragma unroll
        for (int i = 0; i < 8; ++i) {
            const size_t o = ((size_t)(sb * 8 + i) << 14) + (h << 7) + w;
            Q[o] = q[i] + row1[i];
            K[o] = k[i] + row1[8 + i];
            V[o] = v[i] + row1[16 + i];
        }
    }
}

// ---------------------------------------------------------------------------
// Kernel 2: per-plane 128x128 transpose of Q,K,V -> QT,KT,VT. 32x32 LDS
// tiles, coalesced float4 on both sides. grid 1024 x 256.
// ---------------------------------------------------------------------------
__global__ __launch_bounds__(256) void transpose_kernel(
    const float* __restrict__ Q, const float* __restrict__ K,
    const float* __restrict__ V,
    float* __restrict__ QT, float* __restrict__ KT, float* __restrict__ VT)
{
    __shared__ float tile[32 * 33];
    const int bi = blockIdx.x;         // 0..1023
    const int plane = bi >> 4;         // (sb*8+head)
    const int ti = (bi >> 2) & 3, tj = bi & 3;
    const int t = threadIdx.x;
    const int r = t >> 3, c4 = (t & 7) * 4;     // 32 rows x 8 float4 cols
    const size_t pb = (size_t)plane << 14;
    const size_t ibase = pb + (size_t)(ti * 32) * 128 + tj * 32;
    const size_t obase = pb + (size_t)(tj * 32) * 128 + ti * 32;

    const float* srcs[3] = { Q, K, V };
    float* dsts[3] = { QT, KT, VT };
#pragma unroll
    for (int a = 0; a < 3; ++a) {
        const float* src = srcs[a];
        float* dst = dsts[a];
        const float4 val = *(const float4*)&src[ibase + (size_t)r * 128 + c4];
        if (a) __syncthreads();
        tile[r * 33 + c4 + 0] = val.x;
        tile[r * 33 + c4 + 1] = val.y;
        tile[r * 33 + c4 + 2] = val.z;
        tile[r * 33 + c4 + 3] = val.w;
        __syncthreads();
        float4 o;
        o.x = tile[(c4 + 0) * 33 + r];
        o.y = tile[(c4 + 1) * 33 + r];
        o.z = tile[(c4 + 2) * 33 + r];
        o.w = tile[(c4 + 3) * 33 + r];
        *(float4*)&dst[obase + (size_t)r * 128 + c4] = o;
    }
}

// ---------------------------------------------------------------------------
// Kernel 3: both axial attention passes + 8->1 head projection, fused.
// Block = (pass, sb, line), 256 threads = (sub = tid>>7, t = tid&127);
// thread handles heads {sub*4..sub*4+3}; head wave-uniform -> LDS reads are
// broadcast ds_read_b64. K already pre-scaled by log2e. Inner loop on
// packed-FP32 asm: per 4 elems = 2 pk_mul + 4 v_exp + 2 pk_add + 2 pk_fma
// (was 12 scalar VALU + 4 exp). grid 2048 x 256.
// ---------------------------------------------------------------------------
__global__ __launch_bounds__(256) void attn_fused(
    const float* __restrict__ Q, const float* __restrict__ K,
    const float* __restrict__ V,
    const float* __restrict__ QT, const float* __restrict__ KT,
    const float* __restrict__ VT,
    const float* __restrict__ Whor, const float* __restrict__ Wver,
    float* __restrict__ OH, float* __restrict__ OVT)
{
    __shared__ __align__(16) float kk[8 * 128];   // pre-scaled by log2(e)
    __shared__ __align__(16) float vv[8 * 128];
    __shared__ float part[128];                   // sub=1 partial sums

    const int pass = blockIdx.x >> 10;
    const float* __restrict__ Qa = pass ? QT : Q;
    const float* __restrict__ Ka = pass ? KT : K;
    const float* __restrict__ Va = pass ? VT : V;
    const float* __restrict__ wsel = pass ? Wver : Whor;
    float* __restrict__ o = pass ? OVT : OH;

    const int tid  = threadIdx.x;
    const int sub  = tid >> 7;          // head group 0/1 (wave-uniform)
    const int t    = tid & 127;
    const int sbl  = blockIdx.x & 1023;
    const int sb   = sbl >> 7;
    const int line = sbl & 127;

    const size_t base = (((size_t)(sb * 8)) << 14) + ((size_t)line << 7);
    // stage all 8 heads' k,v rows: 256 float4s per array, one per thread.
    {
        const int f  = tid;                       // float4 id, 0..255
        const int hh = f >> 5;                    // head 0..7
        const int tt = (f & 31) << 2;             // element 0..124
        const size_t g = base + ((size_t)hh << 14) + tt;
        ((float4*)kk)[f] = *(const float4*)&Ka[g];
        ((float4*)vv)[f] = *(const float4*)&Va[g];
    }
    __syncthreads();

    float acc = 0.f;
#pragma unroll
    for (int i = 0; i < 4; ++i) {
        const int head = sub * 4 + i;             // wave-uniform
        const float s = Qa[base + ((size_t)head << 14) + t];
        const v2f sv = { s, s };
        const v2f* k2 = (const v2f*)&kk[head << 7];
        const v2f* v2 = (const v2f*)&vv[head << 7];
        v2f d01 = {0.f, 0.f}, d23 = {0.f, 0.f};
        v2f n01 = {0.f, 0.f}, n23 = {0.f, 0.f};
#pragma unroll 8
        for (int l = 0; l < 32; ++l) {
            const v2f k01 = k2[2 * l],     k23 = k2[2 * l + 1];
            const v2f vq01 = v2[2 * l],    vq23 = v2[2 * l + 1];
            const v2f a01 = pk_mul(sv, k01);
            const v2f a23 = pk_mul(sv, k23);
            const v2f e01 = { __builtin_amdgcn_exp2f(a01.x),
                              __builtin_amdgcn_exp2f(a01.y) };
            const v2f e23 = { __builtin_amdgcn_exp2f(a23.x),
                              __builtin_amdgcn_exp2f(a23.y) };
            d01 = pk_add(d01, e01);
            d23 = pk_add(d23, e23);
            n01 = pk_fma(e01, vq01, n01);
            n23 = pk_fma(e23, vq23, n23);
        }
        const v2f dv = pk_add(d01, d23), nv = pk_add(n01, n23);
        const float den = dv.x + dv.y;
        const float num = nv.x + nv.y;
        acc = fmaf(wsel[head], num * __builtin_amdgcn_rcpf(den), acc);
    }

    if (sub) part[t] = acc;
    __syncthreads();
    if (!sub) {
        o[((size_t)sb << 14) + ((size_t)line << 7) + t] = acc + part[t];
    }
}

// ---------------------------------------------------------------------------
// Kernel 4: warp, output-major. Block = (b, cgroup, Y); lane = X. Stores are
// contiguous full-res rows. Both x-taps (cols 2*x0c+dx, 2*x1c+dx) fetched as
// ONE float4 per row at col base cb=min(2*x0c,252) -> 2 dwordx4 per channel
// instead of 4 scalar loads; taps picked with cndmask (hi/up1 select covers
// border clamp). grid 2048 x 256.
// ---------------------------------------------------------------------------
__global__ __launch_bounds__(256) void warp_kernel(
    const float* __restrict__ ref, const float* __restrict__ ovt,
    const float* __restrict__ oh, float* __restrict__ out)
{
    const int bi = blockIdx.x;          // 0..2047
    const int Y  = bi & 255;
    const int cg = (bi >> 8) & 3;
    const int b  = bi >> 10;
    const int X  = threadIdx.x;

    const int dy = Y & 1, dx = X & 1;
    const int p  = dy ? (dx ? 1 : 3) : (dx ? 2 : 0);
    const int sb = p * 2 + b;
    const int h = Y >> 1, w = X >> 1;

    // normalized-coord round trip cancels exactly:
    const float ix = (float)w + oh [((size_t)sb << 14) + (h << 7) + w];
    const float iy = (float)h + ovt[((size_t)sb << 14) + (w << 7) + h];

    const float x0f = floorf(ix), y0f = floorf(iy);
    const float wx = ix - x0f,    wy = iy - y0f;
    const int x0 = (int)x0f, y0 = (int)y0f;
    const int x0c = min(max(x0, 0), 127),     x1c = min(max(x0 + 1, 0), 127);
    const int y0c = min(max(y0, 0), 127),     y1c = min(max(y0 + 1, 0), 127);

    const float w00 = (1.f - wx) * (1.f - wy);
    const float w01 = wx * (1.f - wy);
    const float w10 = (1.f - wx) * wy;
    const float w11 = wx * wy;

    const int cb  = min(2 * x0c, 252);      // float4 col base (8B-aligned ok)
    const bool hi  = (x0c == 127);          // taps live in upper half of f4
    const bool up1 = hi | (x1c != x0c);     // second tap uses upper element
    const int r0 = (2 * y0c + dy) * 256, r1 = (2 * y1c + dy) * 256;
    const int dst = Y * 256 + X;

    const float* rp = ref + ((size_t)b * 64 + cg * 16) * 65536;
    float* op = out + ((size_t)b * 64 + cg * 16) * 65536;

#pragma unroll 4
    for (int c = 0; c < 16; ++c) {
        const size_t pl = (size_t)c * 65536;
        const float4 f0 = *(const float4*)&rp[pl + r0 + cb];
        const float4 f1 = *(const float4*)&rp[pl + r1 + cb];
        const float L0 = dx ? f0.y : f0.x, H0 = dx ? f0.w : f0.z;
        const float L1 = dx ? f1.y : f1.x, H1 = dx ? f1.w : f1.z;
        const float v00 = hi ? H0 : L0,  v01 = up1 ? H0 : L0;
        const float v10 = hi ? H1 : L1,  v11 = up1 ? H1 : L1;
        op[pl + dst] = fmaf(w00, v00, fmaf(w01, v01, fmaf(w10, v10, w11 * v11)));
    }
}

// ---------------------------------------------------------------------------
extern "C" void kernel_launch(void* const* d_in, const int* in_sizes, int n_in,
                              void* d_out, int out_size, void* d_ws, size_t ws_size,
                              hipStream_t stream)
{
    const float* cur  = (const float*)d_in[0];
    const float* ref  = (const float*)d_in[1];
    const float* Wq   = (const float*)d_in[2];
    const float* Wk   = (const float*)d_in[3];
    const float* Wv   = (const float*)d_in[4];
    const float* Wver = (const float*)d_in[5];
    const float* Whor = (const float*)d_in[6];
    float* out = (float*)d_out;

    float* ws = (float*)d_ws;
    const size_t NQ = 8 * 8 * (size_t)PLANE;   // 1,048,576 floats
    float* Q   = ws;
    float* K   = Q  + NQ;                      // pre-scaled by log2(e)
    float* V   = K  + NQ;
    float* QT  = V  + NQ;
    float* KT  = QT + NQ;
    float* VT  = KT + NQ;
    float* OVT = VT + NQ;                      // [sb][w][h]
    float* OH  = OVT + 8 * (size_t)PLANE;      // [sb][h][w]

    qkv_kernel<<<1024, 512, 0, stream>>>(cur, ref, Wq, Wk, Wv, Q, K, V);
    transpose_kernel<<<1024, 256, 0, stream>>>(Q, K, V, QT, KT, VT);
    attn_fused<<<2048, 256, 0, stream>>>(Q, K, V, QT, KT, VT,
                                         Whor, Wver, OH, OVT);
    warp_kernel<<<2048, 256, 0, stream>>>(ref, OVT, OH, out);
}

// Round 3
// 179.238 us; speedup vs baseline: 1.0526x; 1.0526x over previous
//
#include <hip/hip_runtime.h>

// CrossWarpingModule: 4-phase pixel-unshuffle -> axial attention (8 heads, c=1)
// -> flow -> bilinear border grid_sample -> pixel-shuffle back.
// B=2, C=64, H=W=256; sub-images: 8 x [64][128][128].
//
// R10: transpose_kernel DELETED. attn pass-1 stages K/V columns directly from
// the row-major buffers via strided 4B loads (one column per block; the 64B
// lines are shared by the 16 blocks with adjacent w). Pass-1 block IDs are
// remapped so all sharers of a line-group are congruent mod 8 -> same XCD
// under round-robin dispatch -> L2-resident after first touch (L3 backstops).
// Compute loop: b128 LDS reads + packed-FP32 asm math (pk_mul/add/fma).
// kk/vv stride padded to 132 floats (16B-aligned rows, milder write banking).

constexpr int PLANE = 16384;                 // 128*128
constexpr float LOG2E = 1.4426950408889634f;

typedef float v2f __attribute__((ext_vector_type(2)));

// Packed fp32 helpers (full-rate on CDNA; 2 f32 ops / instr).
static __device__ __forceinline__ v2f pk_mul(v2f a, v2f b) {
    v2f d;
    asm("v_pk_mul_f32 %0, %1, %2" : "=v"(d) : "v"(a), "v"(b));
    return d;
}
static __device__ __forceinline__ v2f pk_add(v2f a, v2f b) {
    v2f d;
    asm("v_pk_add_f32 %0, %1, %2" : "=v"(d) : "v"(a), "v"(b));
    return d;
}
static __device__ __forceinline__ v2f pk_fma(v2f a, v2f b, v2f c) {
    v2f d;
    asm("v_pk_fma_f32 %0, %1, %2, %3" : "=v"(d) : "v"(a), "v"(b), "v"(c));
    return d;
}

// ---------------------------------------------------------------------------
// Kernel 1: q/k/v projection. Block = (b, Y, X-half): 128 contiguous X
// positions x 4 channel-groups (16 ch each). Tree-reduce in LDS.
// K is written pre-scaled by log2(e) (consumed only via exp2 in attn).
// grid 1024 x 512.
// ---------------------------------------------------------------------------
__global__ __launch_bounds__(512) void qkv_kernel(
    const float* __restrict__ cur, const float* __restrict__ ref,
    const float* __restrict__ Wq, const float* __restrict__ Wk,
    const float* __restrict__ Wv,
    float* __restrict__ Q, float* __restrict__ K, float* __restrict__ V)
{
    __shared__ float WT[64 * 24];       // WT[c][j]: j<8 Wq, <16 Wk*log2e, <24 Wv
    __shared__ float red0[128 * 25];    // stride 25: conflict-free
    __shared__ float red1[128 * 25];
    const int tid = threadIdx.x;
    for (int i = tid; i < 64 * 24; i += 512) {
        int c = i / 24, j = i % 24;
        float val = (j < 8) ? Wq[j * 64 + c]
                  : (j < 16) ? LOG2E * Wk[(j - 8) * 64 + c]
                  : Wv[(j - 16) * 64 + c];
        WT[c * 24 + j] = val;
    }
    __syncthreads();

    const int bi = blockIdx.x;               // 0..1023
    const int b  = bi >> 9;                  // batch
    const int Y  = (bi >> 1) & 255;          // full-res row
    const int Xh = bi & 1;                   // X half
    const int cg = tid >> 7;                 // channel group 0..3
    const int xi = tid & 127;
    const int X  = Xh * 128 + xi;            // full-res col (contiguous/lane)

    const size_t base_in = (size_t)b * 64 * 65536 + (size_t)Y * 256 + X;
    const float* curp = cur + base_in;
    const float* refp = ref + base_in;

    float q[8], k[8], v[8];
#pragma unroll
    for (int i = 0; i < 8; ++i) { q[i] = 0.f; k[i] = 0.f; v[i] = 0.f; }

    const int c0 = cg * 16;
#pragma unroll 8
    for (int c = 0; c < 16; ++c) {
        float cu = curp[(size_t)(c0 + c) * 65536];
        float rf = refp[(size_t)(c0 + c) * 65536];
        const float* wr = &WT[(c0 + c) * 24];
#pragma unroll
        for (int i = 0; i < 8; ++i) {
            q[i] = fmaf(wr[i],      cu, q[i]);
            k[i] = fmaf(wr[8 + i],  rf, k[i]);
            v[i] = fmaf(wr[16 + i], rf, v[i]);
        }
    }

    // tree reduce: (1 -> red0), (3 -> red1); (2 += red1); (0 += red0+red1)
    float* row0 = &red0[xi * 25];
    float* row1 = &red1[xi * 25];
    if (cg == 1) {
#pragma unroll
        for (int i = 0; i < 8; ++i) {
            row0[i] = q[i]; row0[8 + i] = k[i]; row0[16 + i] = v[i];
        }
    } else if (cg == 3) {
#pragma unroll
        for (int i = 0; i < 8; ++i) {
            row1[i] = q[i]; row1[8 + i] = k[i]; row1[16 + i] = v[i];
        }
    }
    __syncthreads();
    if (cg == 2) {
#pragma unroll
        for (int i = 0; i < 8; ++i) {
            row1[i]      += q[i];
            row1[8 + i]  += k[i];
            row1[16 + i] += v[i];
        }
    } else if (cg == 0) {
#pragma unroll
        for (int i = 0; i < 8; ++i) {
            q[i] += row0[i]; k[i] += row0[8 + i]; v[i] += row0[16 + i];
        }
    }
    __syncthreads();
    if (cg == 0) {
        const int dy = Y & 1, dx = X & 1;
        // (dy,dx)->phase: (0,0)=0 (1,1)=1 (0,1)=2 (1,0)=3
        const int p  = dy ? (dx ? 1 : 3) : (dx ? 2 : 0);
        const int sb = p * 2 + b;
        const int h = Y >> 1, w = X >> 1;
#pragma unroll
        for (int i = 0; i < 8; ++i) {
            const size_t o = ((size_t)(sb * 8 + i) << 14) + (h << 7) + w;
            Q[o] = q[i] + row1[i];
            K[o] = k[i] + row1[8 + i];
            V[o] = v[i] + row1[16 + i];
        }
    }
}

// ---------------------------------------------------------------------------
// Kernel 2: both axial attention passes + 8->1 head projection, fused.
// Block = (pass, sb, line), 256 threads = (sub = tid>>7, t = tid&127);
// thread handles heads {sub*4..sub*4+3}; head wave-uniform -> LDS reads are
// broadcast ds_read_b128. K pre-scaled by log2e. Packed-FP32 math.
//
// Pass 0 (horizontal): line = row h; K/V rows staged with float4 loads.
// Pass 1 (vertical):   line = col w; K/V columns staged with strided 4B
//   loads (4 rows per thread assembled into one ds_write_b128). Pass-1
//   block IDs encoded as P = (w>>4) + 8*sb + 64*(w&15) so the 16 blocks
//   sharing each 64B line-group (and all sb's of a w-group) satisfy
//   P % 8 == (w>>4)%8 -> same XCD under round-robin -> L2 line reuse.
// grid 2048 x 256.
// ---------------------------------------------------------------------------
__global__ __launch_bounds__(256) void attn_fused(
    const float* __restrict__ Q, const float* __restrict__ K,
    const float* __restrict__ V,
    const float* __restrict__ Whor, const float* __restrict__ Wver,
    float* __restrict__ OH, float* __restrict__ OVT)
{
    __shared__ __align__(16) float kk[8 * 132];   // stride 132: 16B-aligned rows
    __shared__ __align__(16) float vv[8 * 132];
    __shared__ float part[128];                   // sub=1 partial sums

    const int pass = blockIdx.x >> 10;
    const int P    = blockIdx.x & 1023;
    int sb, line;
    if (!pass) {
        sb   = P >> 7;
        line = P & 127;
    } else {
        // P = (w>>4) + 8*sb + 64*(w&15)  (bijective over [0,1024))
        const int w4 = P & 7, wl = P >> 6;
        sb   = (P >> 3) & 7;
        line = (w4 << 4) | wl;                    // w
    }
    const float* __restrict__ wsel = pass ? Wver : Whor;
    float* __restrict__ o = pass ? OVT : OH;

    const int tid = threadIdx.x;
    const int sub = tid >> 7;           // head group 0/1 (wave-uniform)
    const int t   = tid & 127;
    const size_t sbb = ((size_t)(sb * 8)) << 14;  // base of sb's 8 planes

    // ---- stage K/V (8 heads x 128 elems each) ----
    {
        const int hh = tid >> 5;                  // head 0..7
        const int fi = tid & 31;                  // quad id within head
        if (!pass) {
            const size_t g = sbb + ((size_t)hh << 14) + ((size_t)line << 7) + (fi << 2);
            *(float4*)&kk[hh * 132 + (fi << 2)] = *(const float4*)&K[g];
            *(float4*)&vv[hh * 132 + (fi << 2)] = *(const float4*)&V[g];
        } else {
            // column `line`: rows fi*4 .. fi*4+3 of head hh
            const size_t g = sbb + ((size_t)hh << 14) + ((size_t)(fi << 2) << 7) + line;
            float4 kq, vq;
            kq.x = K[g];       kq.y = K[g + 128];
            kq.z = K[g + 256]; kq.w = K[g + 384];
            vq.x = V[g];       vq.y = V[g + 128];
            vq.z = V[g + 256]; vq.w = V[g + 384];
            *(float4*)&kk[hh * 132 + (fi << 2)] = kq;
            *(float4*)&vv[hh * 132 + (fi << 2)] = vq;
        }
    }
    __syncthreads();

    // per-thread Q pointer: pass0 -> (row line, elem t); pass1 -> (row t, col line)
    const float* __restrict__ sQ = pass
        ? &Q[sbb + ((size_t)t << 7) + line]
        : &Q[sbb + ((size_t)line << 7) + t];

    float acc = 0.f;
#pragma unroll
    for (int i = 0; i < 4; ++i) {
        const int head = sub * 4 + i;             // wave-uniform
        const float s = sQ[(size_t)head << 14];
        const v2f sv = { s, s };
        const float4* k4 = (const float4*)&kk[head * 132];
        const float4* v4 = (const float4*)&vv[head * 132];
        v2f d01 = {0.f, 0.f}, d23 = {0.f, 0.f};
        v2f n01 = {0.f, 0.f}, n23 = {0.f, 0.f};
#pragma unroll 8
        for (int l = 0; l < 32; ++l) {
            const float4 kq = k4[l];
            const float4 vq = v4[l];
            const v2f a01 = pk_mul(sv, (v2f){kq.x, kq.y});
            const v2f a23 = pk_mul(sv, (v2f){kq.z, kq.w});
            const v2f e01 = { __builtin_amdgcn_exp2f(a01.x),
                              __builtin_amdgcn_exp2f(a01.y) };
            const v2f e23 = { __builtin_amdgcn_exp2f(a23.x),
                              __builtin_amdgcn_exp2f(a23.y) };
            d01 = pk_add(d01, e01);
            d23 = pk_add(d23, e23);
            n01 = pk_fma(e01, (v2f){vq.x, vq.y}, n01);
            n23 = pk_fma(e23, (v2f){vq.z, vq.w}, n23);
        }
        const v2f dv = pk_add(d01, d23), nv = pk_add(n01, n23);
        const float den = dv.x + dv.y;
        const float num = nv.x + nv.y;
        acc = fmaf(wsel[head], num * __builtin_amdgcn_rcpf(den), acc);
    }

    if (sub) part[t] = acc;
    __syncthreads();
    if (!sub) {
        o[((size_t)sb << 14) + ((size_t)line << 7) + t] = acc + part[t];
    }
}

// ---------------------------------------------------------------------------
// Kernel 3: warp, output-major. Block = (b, cgroup, Y); lane = X. Stores are
// contiguous full-res rows. Both x-taps (cols 2*x0c+dx, 2*x1c+dx) fetched as
// ONE float4 per row at col base cb=min(2*x0c,252) -> 2 dwordx4 per channel
// instead of 4 scalar loads; taps picked with cndmask (hi/up1 select covers
// border clamp). grid 2048 x 256.
// ---------------------------------------------------------------------------
__global__ __launch_bounds__(256) void warp_kernel(
    const float* __restrict__ ref, const float* __restrict__ ovt,
    const float* __restrict__ oh, float* __restrict__ out)
{
    const int bi = blockIdx.x;          // 0..2047
    const int Y  = bi & 255;
    const int cg = (bi >> 8) & 3;
    const int b  = bi >> 10;
    const int X  = threadIdx.x;

    const int dy = Y & 1, dx = X & 1;
    const int p  = dy ? (dx ? 1 : 3) : (dx ? 2 : 0);
    const int sb = p * 2 + b;
    const int h = Y >> 1, w = X >> 1;

    // normalized-coord round trip cancels exactly:
    const float ix = (float)w + oh [((size_t)sb << 14) + (h << 7) + w];
    const float iy = (float)h + ovt[((size_t)sb << 14) + (w << 7) + h];

    const float x0f = floorf(ix), y0f = floorf(iy);
    const float wx = ix - x0f,    wy = iy - y0f;
    const int x0 = (int)x0f, y0 = (int)y0f;
    const int x0c = min(max(x0, 0), 127),     x1c = min(max(x0 + 1, 0), 127);
    const int y0c = min(max(y0, 0), 127),     y1c = min(max(y0 + 1, 0), 127);

    const float w00 = (1.f - wx) * (1.f - wy);
    const float w01 = wx * (1.f - wy);
    const float w10 = (1.f - wx) * wy;
    const float w11 = wx * wy;

    const int cb  = min(2 * x0c, 252);      // float4 col base (8B-aligned ok)
    const bool hi  = (x0c == 127);          // taps live in upper half of f4
    const bool up1 = hi | (x1c != x0c);     // second tap uses upper element
    const int r0 = (2 * y0c + dy) * 256, r1 = (2 * y1c + dy) * 256;
    const int dst = Y * 256 + X;

    const float* rp = ref + ((size_t)b * 64 + cg * 16) * 65536;
    float* op = out + ((size_t)b * 64 + cg * 16) * 65536;

#pragma unroll 4
    for (int c = 0; c < 16; ++c) {
        const size_t pl = (size_t)c * 65536;
        const float4 f0 = *(const float4*)&rp[pl + r0 + cb];
        const float4 f1 = *(const float4*)&rp[pl + r1 + cb];
        const float L0 = dx ? f0.y : f0.x, H0 = dx ? f0.w : f0.z;
        const float L1 = dx ? f1.y : f1.x, H1 = dx ? f1.w : f1.z;
        const float v00 = hi ? H0 : L0,  v01 = up1 ? H0 : L0;
        const float v10 = hi ? H1 : L1,  v11 = up1 ? H1 : L1;
        op[pl + dst] = fmaf(w00, v00, fmaf(w01, v01, fmaf(w10, v10, w11 * v11)));
    }
}

// ---------------------------------------------------------------------------
extern "C" void kernel_launch(void* const* d_in, const int* in_sizes, int n_in,
                              void* d_out, int out_size, void* d_ws, size_t ws_size,
                              hipStream_t stream)
{
    const float* cur  = (const float*)d_in[0];
    const float* ref  = (const float*)d_in[1];
    const float* Wq   = (const float*)d_in[2];
    const float* Wk   = (const float*)d_in[3];
    const float* Wv   = (const float*)d_in[4];
    const float* Wver = (const float*)d_in[5];
    const float* Whor = (const float*)d_in[6];
    float* out = (float*)d_out;

    float* ws = (float*)d_ws;
    const size_t NQ = 8 * 8 * (size_t)PLANE;   // 1,048,576 floats
    float* Q   = ws;
    float* K   = Q  + NQ;                      // pre-scaled by log2(e)
    float* V   = K  + NQ;
    float* OVT = V  + NQ;                      // [sb][w][h]
    float* OH  = OVT + 8 * (size_t)PLANE;      // [sb][h][w]

    qkv_kernel<<<1024, 512, 0, stream>>>(cur, ref, Wq, Wk, Wv, Q, K, V);
    attn_fused<<<2048, 256, 0, stream>>>(Q, K, V, Whor, Wver, OH, OVT);
    warp_kernel<<<2048, 256, 0, stream>>>(ref, OVT, OH, out);
}